// Round 6
// baseline (147.560 us; speedup 1.0000x reference)
//
#include <hip/hip_runtime.h>
#include <stdint.h>

typedef __attribute__((ext_vector_type(4)))  float    f32x4;
typedef __attribute__((ext_vector_type(16))) float    f32x16;
typedef __attribute__((ext_vector_type(8)))  _Float16 f16x8;
typedef __attribute__((ext_vector_type(8)))  __bf16   bf16x8;

#define SEQ   2048
#define DH    64
#define BQ    128            // q rows per block (4 waves x 32)
#define BK    64             // keys per tile
#define NT    (SEQ / BK)     // 32 k-tiles per batch
#define HT    (NT / 2)       // 16 tiles per split-K block
#define ROWE  72             // padded row: 144 B stride (16B-aligned, proven 0-conflict)
#define TILEE (64 * ROWE)    // 4608 elems = 9216 B per tile
#define L2E   1.44269504088896340736f

#if __has_builtin(__builtin_amdgcn_exp2f)
static __device__ __forceinline__ float fast_exp2(float x) { return __builtin_amdgcn_exp2f(x); }
#else
static __device__ __forceinline__ float fast_exp2(float x) {
  float r; asm("v_exp_f32 %0, %1" : "=v"(r) : "v"(x)); return r;
}
#endif
static __device__ __forceinline__ uint32_t pack2_bf16(float a, float b) {
  union { __bf16 h[2]; uint32_t u; } cv;
  cv.h[0] = (__bf16)a; cv.h[1] = (__bf16)b;
  return cv.u;
}
union frag_u { uint32_t u[4]; bf16x8 v; };

typedef const __attribute__((address_space(1))) uint32_t* gp1_t;
typedef __attribute__((address_space(3))) uint32_t*       lp3_t;

// sigma relabel: S^T=K*Q^T's C-layout row m (= b+4h+8c) is made to carry key
// sigma(m) = 16*(c&1) + 8*h + 4*(c>>1) + b. Then each lane's 16 C-values are
// exactly the natural-key-order A-fragment slices for P*V — the C->A transform
// is pure register repacking: no LDS round-trip, no cross-lane ops.
__host__ __device__ inline int sigma32(int m) {
  int b = m & 3, h = (m >> 2) & 1, c = m >> 3;
  return ((c & 1) << 4) | (h << 3) | ((c >> 1) << 2) | b;
}

// ---------------- pre-pass: K -> f16 padded tiles with sigma row relabel;
// V -> bf16 transposed (natural key order) padded tiles
__global__ __launch_bounds__(256)
void prepass(const float* __restrict__ K, const float* __restrict__ V,
             _Float16* __restrict__ Kh, __bf16* __restrict__ Vh) {
  const int blk = blockIdx.x;
  const int tid = threadIdx.x;
  if (blk < 32 * NT) {
    const float* src = K + ((size_t)(blk >> 5) * SEQ + (size_t)(blk & 31) * 64) * DH;
    _Float16*    dst = Kh + (size_t)blk * TILEE;
    const int row = tid >> 2, c = (tid & 3) << 4;
    const int srow = (row & 32) | sigma32(row & 31);   // row holds key sigma(row)
    const float* sp = src + srow * DH + c;
    f32x4 x0 = *(const f32x4*)(sp + 0),  x1 = *(const f32x4*)(sp + 4);
    f32x4 x2 = *(const f32x4*)(sp + 8),  x3 = *(const f32x4*)(sp + 12);
    f16x8 h0, h1;
#pragma unroll
    for (int j = 0; j < 4; ++j) {
      h0[j] = (_Float16)x0[j]; h0[j + 4] = (_Float16)x1[j];
      h1[j] = (_Float16)x2[j]; h1[j + 4] = (_Float16)x3[j];
    }
    *(f16x8*)(dst + row * ROWE + c)     = h0;
    *(f16x8*)(dst + row * ROWE + c + 8) = h1;
  } else {
    const int blk2 = blk - 32 * NT;
    const float* src = V + ((size_t)(blk2 >> 5) * SEQ + (size_t)(blk2 & 31) * 64) * DH;
    __bf16*      dst = Vh + (size_t)blk2 * TILEE;
#pragma unroll
    for (int it = 0; it < 4; ++it) {
      int task = tid + it * 256;
      int d = task & 63, g = task >> 6;      // 16 key-groups x 64 d
      const float* sp = src + (size_t)(4 * g) * DH + d;   // coalesced across d
      __bf16 hv[4];
#pragma unroll
      for (int j = 0; j < 4; ++j) hv[j] = (__bf16)sp[(size_t)j * DH];
      *(uint64_t*)(dst + d * ROWE + 4 * g) = *(uint64_t*)hv;
    }
  }
}

// ---------------- main: split-K flash attention, double-buffered DMA tiles,
// no P LDS round-trip (sigma trick). Writes unnormalized bf16 partials.
__global__ __launch_bounds__(256, 4)
void flash_attn_v6(const float* __restrict__ Q, const _Float16* __restrict__ Kh,
                   const __bf16* __restrict__ Vh, __bf16* __restrict__ Opart,
                   float* __restrict__ lpart) {
  __shared__ _Float16 Ksb[2][64][ROWE];   // 18432 B
  __shared__ __bf16   Vtb[2][64][ROWE];   // 18432 B  -> 36.9 KB total: 4 blocks/CU

  const int tid  = threadIdx.x;
  const int wv   = tid >> 6;
  const int lane = tid & 63;
  const int hfw  = lane >> 5;
  const int l31  = lane & 31;

  const int batch = blockIdx.x & 31;      // batch-major for XCD L2 locality
  const int rest  = blockIdx.x >> 5;
  const int qblk  = rest & 15;
  const int kg    = rest >> 4;            // split-K half: tiles [kg*HT, kg*HT+HT)

  const float* Qb = Q + (size_t)batch * SEQ * DH;
  const uint32_t* Kt0 = (const uint32_t*)(Kh + (size_t)batch * NT * TILEE);
  const uint32_t* Vt0 = (const uint32_t*)(Vh + (size_t)batch * NT * TILEE);

  auto stage = [&](int t, int buf) {
    const uint32_t* kgp = Kt0 + (size_t)t * (TILEE / 2);
    const uint32_t* vgp = Vt0 + (size_t)t * (TILEE / 2);
    lp3_t kl = (lp3_t)&Ksb[buf][0][0];
    lp3_t vl = (lp3_t)&Vtb[buf][0][0];
#pragma unroll
    for (int j = wv; j < 9; j += 4) {
      __builtin_amdgcn_global_load_lds((gp1_t)(kgp + j * 256 + lane * 4), kl + j * 256, 16, 0, 0);
      __builtin_amdgcn_global_load_lds((gp1_t)(vgp + j * 256 + lane * 4), vl + j * 256, 16, 0, 0);
    }
  };

  // Q fragments (B-operand of S^T): lane holds Q[q=l31][d=ks*16+hfw*8+j], *log2e
  const int qrow = qblk * BQ + wv * 32 + l31;
  f16x8 qf[4];
  {
    const float* qp = Qb + (size_t)qrow * DH + hfw * 8;
#pragma unroll
    for (int ks = 0; ks < 4; ++ks) {
      f32x4 a = *(const f32x4*)(qp + ks * 16);
      f32x4 b = *(const f32x4*)(qp + ks * 16 + 4);
#pragma unroll
      for (int j = 0; j < 4; ++j) {
        qf[ks][j]     = (_Float16)(a[j] * L2E);
        qf[ks][j + 4] = (_Float16)(b[j] * L2E);
      }
    }
  }

  f32x16 acc0 = {}, acc1 = {};   // O partial, C-layout: col = d = l31 (+32), rows = q
  float lsum = 0.f;              // partial row-sum for q = l31 (this lane's keys)

  stage(kg * HT, 0);

  for (int i = 0; i < HT; ++i) {
    __syncthreads();   // vmcnt(0) drain: tile i resident; all waves done with i-1
    if (i + 1 < HT) stage(kg * HT + i + 1, (i + 1) & 1);
    const int buf = i & 1;

    // ---- S^T = K·Q^T (sigma-relabeled K rows): C col = q = l31, rows = keys
    f32x16 s0 = {}, s1 = {};
#pragma unroll
    for (int ks = 0; ks < 4; ++ks) {
      int dof = ks * 16 + hfw * 8;
      f16x8 kf0 = *(const f16x8*)&Ksb[buf][l31][dof];
      f16x8 kf1 = *(const f16x8*)&Ksb[buf][l31 + 32][dof];
      s0 = __builtin_amdgcn_mfma_f32_32x32x16_f16(kf0, qf[ks], s0, 0, 0, 0);  // keys 0..31
      s1 = __builtin_amdgcn_mfma_f32_32x32x16_f16(kf1, qf[ks], s1, 0, 0, 0);  // keys 32..63
    }

    // ---- P = exp2(S); repack in-register into natural-key-order A-fragments.
    // sigma guarantees: this lane's p[j] are exactly keys {16k + 8*hfw + 0..7}.
    frag_u fr[4];
#pragma unroll
    for (int t2 = 0; t2 < 2; ++t2) {
      const f32x16& s = t2 ? s1 : s0;
      float p[16];
#pragma unroll
      for (int j = 0; j < 16; ++j) p[j] = fast_exp2(s[j]);
      float a0 = (p[0] + p[1]) + (p[2] + p[3]);
      float a1 = (p[4] + p[5]) + (p[6] + p[7]);
      float a2 = (p[8] + p[9]) + (p[10] + p[11]);
      float a3 = (p[12] + p[13]) + (p[14] + p[15]);
      lsum += (a0 + a1) + (a2 + a3);
      fr[2 * t2    ].u[0] = pack2_bf16(p[0],  p[1]);
      fr[2 * t2    ].u[1] = pack2_bf16(p[2],  p[3]);
      fr[2 * t2    ].u[2] = pack2_bf16(p[8],  p[9]);
      fr[2 * t2    ].u[3] = pack2_bf16(p[10], p[11]);
      fr[2 * t2 + 1].u[0] = pack2_bf16(p[4],  p[5]);
      fr[2 * t2 + 1].u[1] = pack2_bf16(p[6],  p[7]);
      fr[2 * t2 + 1].u[2] = pack2_bf16(p[12], p[13]);
      fr[2 * t2 + 1].u[3] = pack2_bf16(p[14], p[15]);
    }

    // ---- O += P·V : A = P frags (registers, natural key order), B = V^T (LDS)
#pragma unroll
    for (int ks = 0; ks < 4; ++ks) {
      int kof = ks * 16 + hfw * 8;
      bf16x8 v0 = *(const bf16x8*)&Vtb[buf][l31][kof];
      bf16x8 v1 = *(const bf16x8*)&Vtb[buf][l31 + 32][kof];
      acc0 = __builtin_amdgcn_mfma_f32_32x32x16_bf16(fr[ks].v, v0, acc0, 0, 0, 0);
      acc1 = __builtin_amdgcn_mfma_f32_32x32x16_bf16(fr[ks].v, v1, acc1, 0, 0, 0);
    }
  }

  // ---- store unnormalized partials (bf16 O, fp32 lsum); combine kernel finishes
  float tot = lsum + __shfl_xor(lsum, 32);   // q = l31's full partial over kg's keys
  const size_t qg = (size_t)batch * SEQ + qblk * BQ;
  lpart[(size_t)kg * 32 * SEQ + qg + wv * 32 + l31] = tot;  // both halves write same value
  __bf16* op = Opart + (size_t)kg * 32 * SEQ * DH;
#pragma unroll
  for (int j = 0; j < 16; ++j) {
    int row = (j & 3) + 8 * (j >> 2) + 4 * hfw;
    size_t off = (qg + wv * 32 + row) * DH + l31;
    op[off]      = (__bf16)acc0[j];
    op[off + 32] = (__bf16)acc1[j];
  }
}

// ---------------- combine: O = (O0 + O1) / (l0 + l1)
__global__ __launch_bounds__(256)
void combine(const __bf16* __restrict__ Opart, const float* __restrict__ lpart,
             float* __restrict__ O) {
  const size_t gid  = (size_t)blockIdx.x * 256 + threadIdx.x;
  const size_t base = gid * 8;                  // 8 d-elems within one q-row
  const size_t qidx = base >> 6;
  bf16x8 a0 = *(const bf16x8*)(Opart + base);
  bf16x8 a1 = *(const bf16x8*)(Opart + (size_t)32 * SEQ * DH + base);
  float inv = 1.0f / (lpart[qidx] + lpart[(size_t)32 * SEQ + qidx]);
  f32x4 o0, o1;
#pragma unroll
  for (int j = 0; j < 4; ++j) {
    o0[j] = ((float)a0[j] + (float)a1[j]) * inv;
    o1[j] = ((float)a0[j + 4] + (float)a1[j + 4]) * inv;
  }
  *(f32x4*)(O + base)     = o0;
  *(f32x4*)(O + base + 4) = o1;
}

extern "C" void kernel_launch(void* const* d_in, const int* in_sizes, int n_in,
                              void* d_out, int out_size, void* d_ws, size_t ws_size,
                              hipStream_t stream) {
  (void)in_sizes; (void)n_in; (void)ws_size; (void)out_size;
  const float* q = (const float*)d_in[0];
  const float* k = (const float*)d_in[1];
  const float* v = (const float*)d_in[2];
  float* o = (float*)d_out;
  // ws layout: Kh 9.44 MB | Vh 9.44 MB | Opart bf16 16.8 MB | lpart 512 KB  (~36 MB)
  char* w = (char*)d_ws;
  _Float16* Kh    = (_Float16*)w;                    w += (size_t)32 * NT * TILEE * 2;
  __bf16*   Vh    = (__bf16*)w;                      w += (size_t)32 * NT * TILEE * 2;
  __bf16*   Opart = (__bf16*)w;                      w += (size_t)2 * 32 * SEQ * DH * 2;
  float*    lpart = (float*)w;

  prepass<<<dim3(2 * 32 * NT), dim3(256), 0, stream>>>(k, v, Kh, Vh);
  flash_attn_v6<<<dim3(32 * 16 * 2), dim3(256), 0, stream>>>(q, Kh, Vh, Opart, lpart);
  combine<<<dim3((32 * SEQ * DH) / (256 * 8)), dim3(256), 0, stream>>>(Opart, lpart, o);
}

// Round 9
// 138.680 us; speedup vs baseline: 1.0640x; 1.0640x over previous
//
#include <hip/hip_runtime.h>
#include <stdint.h>

typedef __attribute__((ext_vector_type(4)))  float    f32x4;
typedef __attribute__((ext_vector_type(16))) float    f32x16;
typedef __attribute__((ext_vector_type(8)))  _Float16 f16x8;
typedef __attribute__((ext_vector_type(8)))  __bf16   bf16x8;

#define SEQ   2048
#define DH    64
#define BQ    128            // q rows per block (4 waves x 32)
#define BK    64             // keys per tile
#define NT    (SEQ / BK)     // 32 k-tiles per batch
#define ROWE  72             // padded row: 144 B stride (16B-aligned, proven 0-conflict)
#define TILEE (64 * ROWE)    // 4608 elems = 9216 B per tile
#define L2E   1.44269504088896340736f

#if __has_builtin(__builtin_amdgcn_exp2f)
static __device__ __forceinline__ float fast_exp2(float x) { return __builtin_amdgcn_exp2f(x); }
#else
static __device__ __forceinline__ float fast_exp2(float x) {
  float r; asm("v_exp_f32 %0, %1" : "=v"(r) : "v"(x)); return r;
}
#endif
static __device__ __forceinline__ uint32_t pack2_bf16(float a, float b) {
  union { __bf16 h[2]; uint32_t u; } cv;
  cv.h[0] = (__bf16)a; cv.h[1] = (__bf16)b;
  return cv.u;
}
union frag_u { uint32_t u[4]; bf16x8 v; };

typedef const __attribute__((address_space(1))) uint32_t* gp1_t;
typedef __attribute__((address_space(3))) uint32_t*       lp3_t;

// sigma relabel: S^T=K*Q^T's C-layout row m (= b+4h+8c) is made to carry key
// sigma(m) = 16*(c&1) + 8*h + 4*(c>>1) + b. Then each lane's 16 C-values are
// exactly the natural-key-order A-fragment slices for P*V — the C->A transform
// is pure register repacking (HW-verified in R6: absmax 0.03125).
__host__ __device__ inline int sigma32(int m) {
  int b = m & 3, h = (m >> 2) & 1, c = m >> 3;
  return ((c & 1) << 4) | (h << 3) | ((c >> 1) << 2) | b;
}

// ---------------- pre-pass (verbatim from passing R6): K -> f16 padded tiles
// with sigma row relabel; V -> bf16 transposed (natural key order) padded tiles
__global__ __launch_bounds__(256)
void prepass(const float* __restrict__ K, const float* __restrict__ V,
             _Float16* __restrict__ Kh, __bf16* __restrict__ Vh) {
  const int blk = blockIdx.x;
  const int tid = threadIdx.x;
  if (blk < 32 * NT) {
    const float* src = K + ((size_t)(blk >> 5) * SEQ + (size_t)(blk & 31) * 64) * DH;
    _Float16*    dst = Kh + (size_t)blk * TILEE;
    const int row = tid >> 2, c = (tid & 3) << 4;
    const int srow = (row & 32) | sigma32(row & 31);   // row holds key sigma(row)
    const float* sp = src + srow * DH + c;
    f32x4 x0 = *(const f32x4*)(sp + 0),  x1 = *(const f32x4*)(sp + 4);
    f32x4 x2 = *(const f32x4*)(sp + 8),  x3 = *(const f32x4*)(sp + 12);
    f16x8 h0, h1;
#pragma unroll
    for (int j = 0; j < 4; ++j) {
      h0[j] = (_Float16)x0[j]; h0[j + 4] = (_Float16)x1[j];
      h1[j] = (_Float16)x2[j]; h1[j + 4] = (_Float16)x3[j];
    }
    *(f16x8*)(dst + row * ROWE + c)     = h0;
    *(f16x8*)(dst + row * ROWE + c + 8) = h1;
  } else {
    const int blk2 = blk - 32 * NT;
    const float* src = V + ((size_t)(blk2 >> 5) * SEQ + (size_t)(blk2 & 31) * 64) * DH;
    __bf16*      dst = Vh + (size_t)blk2 * TILEE;
#pragma unroll
    for (int it = 0; it < 4; ++it) {
      int task = tid + it * 256;
      int d = task & 63, g = task >> 6;      // 16 key-groups x 64 d
      const float* sp = src + (size_t)(4 * g) * DH + d;   // coalesced across d
      __bf16 hv[4];
#pragma unroll
      for (int j = 0; j < 4; ++j) hv[j] = (__bf16)sp[(size_t)j * DH];
      *(uint64_t*)(dst + d * ROWE + 4 * g) = *(uint64_t*)hv;
    }
  }
}

// ---------------- main: full-K flash attention (no split-K), double-buffered
// DMA tiles, sigma register repack, direct normalized fp32 O store
__global__ __launch_bounds__(256, 2)
void flash_attn_v9(const float* __restrict__ Q, const _Float16* __restrict__ Kh,
                   const __bf16* __restrict__ Vh, float* __restrict__ O) {
  __shared__ _Float16 Ksb[2][64][ROWE];   // 18432 B
  __shared__ __bf16   Vtb[2][64][ROWE];   // 18432 B
  __shared__ float    Ls[4][32];          // per-wave 1/rowsum broadcast (epilogue)

  const int tid  = threadIdx.x;
  const int wv   = tid >> 6;
  const int lane = tid & 63;
  const int hfw  = lane >> 5;
  const int l31  = lane & 31;

  const int batch = blockIdx.x & 31;      // batch-major for XCD L2 locality
  const int qblk  = blockIdx.x >> 5;      // 16 q-blocks of 128 rows

  const float* Qb = Q + (size_t)batch * SEQ * DH;
  float*       Ob = O + (size_t)batch * SEQ * DH;
  const uint32_t* Kt0 = (const uint32_t*)(Kh + (size_t)batch * NT * TILEE);
  const uint32_t* Vt0 = (const uint32_t*)(Vh + (size_t)batch * NT * TILEE);

  // DMA: LDS dest is wave-uniform base (HW adds lane*16) — proven pattern (R6)
  auto stage = [&](int t, int buf) {
    const uint32_t* kgp = Kt0 + (size_t)t * (TILEE / 2);
    const uint32_t* vgp = Vt0 + (size_t)t * (TILEE / 2);
    lp3_t kl = (lp3_t)&Ksb[buf][0][0];
    lp3_t vl = (lp3_t)&Vtb[buf][0][0];
#pragma unroll
    for (int j = wv; j < 9; j += 4) {
      __builtin_amdgcn_global_load_lds((gp1_t)(kgp + j * 256 + lane * 4), kl + j * 256, 16, 0, 0);
      __builtin_amdgcn_global_load_lds((gp1_t)(vgp + j * 256 + lane * 4), vl + j * 256, 16, 0, 0);
    }
  };

  // Q fragments (B-operand of S^T): lane holds Q[q=l31][d=ks*16+hfw*8+j], *log2e
  const int qrow = qblk * BQ + wv * 32 + l31;
  f16x8 qf[4];
  {
    const float* qp = Qb + (size_t)qrow * DH + hfw * 8;
#pragma unroll
    for (int ks = 0; ks < 4; ++ks) {
      f32x4 a = *(const f32x4*)(qp + ks * 16);
      f32x4 b = *(const f32x4*)(qp + ks * 16 + 4);
#pragma unroll
      for (int j = 0; j < 4; ++j) {
        qf[ks][j]     = (_Float16)(a[j] * L2E);
        qf[ks][j + 4] = (_Float16)(b[j] * L2E);
      }
    }
  }

  f32x16 acc0 = {}, acc1 = {};   // O: col = d = l31 / l31+32, rows = q (C-layout)
  float lsum = 0.f;              // row-sum for q = l31 over this lane's keys

  stage(0, 0);

  for (int i = 0; i < NT; ++i) {
    __syncthreads();   // vmcnt(0) drain: tile i resident; all waves done with i-1
    if (i + 1 < NT) stage(i + 1, (i + 1) & 1);
    const int buf = i & 1;

    // ---- S^T = K·Q^T (sigma-relabeled K rows): C col = q = l31, rows = keys
    f32x16 s0 = {}, s1 = {};
#pragma unroll
    for (int ks = 0; ks < 4; ++ks) {
      int dof = ks * 16 + hfw * 8;
      f16x8 kf0 = *(const f16x8*)&Ksb[buf][l31][dof];
      f16x8 kf1 = *(const f16x8*)&Ksb[buf][l31 + 32][dof];
      s0 = __builtin_amdgcn_mfma_f32_32x32x16_f16(kf0, qf[ks], s0, 0, 0, 0);  // keys 0..31
      s1 = __builtin_amdgcn_mfma_f32_32x32x16_f16(kf1, qf[ks], s1, 0, 0, 0);  // keys 32..63
    }

    // ---- P = exp2(S); repack into natural-key-order A-fragments (registers)
    frag_u fr[4];
#pragma unroll
    for (int t2 = 0; t2 < 2; ++t2) {
      const f32x16& s = t2 ? s1 : s0;
      float p[16];
#pragma unroll
      for (int j = 0; j < 16; ++j) p[j] = fast_exp2(s[j]);
      float a0 = (p[0] + p[1]) + (p[2] + p[3]);
      float a1 = (p[4] + p[5]) + (p[6] + p[7]);
      float a2 = (p[8] + p[9]) + (p[10] + p[11]);
      float a3 = (p[12] + p[13]) + (p[14] + p[15]);
      lsum += (a0 + a1) + (a2 + a3);
      fr[2 * t2    ].u[0] = pack2_bf16(p[0],  p[1]);
      fr[2 * t2    ].u[1] = pack2_bf16(p[2],  p[3]);
      fr[2 * t2    ].u[2] = pack2_bf16(p[8],  p[9]);
      fr[2 * t2    ].u[3] = pack2_bf16(p[10], p[11]);
      fr[2 * t2 + 1].u[0] = pack2_bf16(p[4],  p[5]);
      fr[2 * t2 + 1].u[1] = pack2_bf16(p[6],  p[7]);
      fr[2 * t2 + 1].u[2] = pack2_bf16(p[12], p[13]);
      fr[2 * t2 + 1].u[3] = pack2_bf16(p[14], p[15]);
    }

    // ---- O += P·V : A = P frags (registers, natural key order), B = V^T (LDS)
#pragma unroll
    for (int ks = 0; ks < 4; ++ks) {
      int kof = ks * 16 + hfw * 8;
      bf16x8 v0 = *(const bf16x8*)&Vtb[buf][l31][kof];
      bf16x8 v1 = *(const bf16x8*)&Vtb[buf][l31 + 32][kof];
      acc0 = __builtin_amdgcn_mfma_f32_32x32x16_bf16(fr[ks].v, v0, acc0, 0, 0, 0);
      acc1 = __builtin_amdgcn_mfma_f32_32x32x16_bf16(fr[ks].v, v1, acc1, 0, 0, 0);
    }
  }

  // ---- epilogue (proven R2 pattern): combine half-wave partial row-sums for
  // q=l31, publish 1/sum per-wave via LDS (same-wave write->read), store fp32
  float tot = lsum + __shfl_xor(lsum, 32);
  Ls[wv][l31] = __builtin_amdgcn_rcpf(tot);
#pragma unroll
  for (int j = 0; j < 16; ++j) {
    int row = (j & 3) + 8 * (j >> 2) + 4 * hfw;
    float inv = Ls[wv][row];
    size_t off = (size_t)(qblk * BQ + wv * 32 + row) * DH + l31;
    Ob[off]      = acc0[j] * inv;
    Ob[off + 32] = acc1[j] * inv;
  }
}

extern "C" void kernel_launch(void* const* d_in, const int* in_sizes, int n_in,
                              void* d_out, int out_size, void* d_ws, size_t ws_size,
                              hipStream_t stream) {
  (void)in_sizes; (void)n_in; (void)ws_size; (void)out_size;
  const float* q = (const float*)d_in[0];
  const float* k = (const float*)d_in[1];
  const float* v = (const float*)d_in[2];
  float* o = (float*)d_out;
  // ws: Kh 9.44 MB | Vh 9.44 MB  (~18.9 MB total)
  _Float16* Kh = (_Float16*)d_ws;
  __bf16*   Vh = (__bf16*)((char*)d_ws + (size_t)32 * NT * TILEE * sizeof(_Float16));

  prepass<<<dim3(2 * 32 * NT), dim3(256), 0, stream>>>(k, v, Kh, Vh);
  flash_attn_v9<<<dim3(32 * (SEQ / BQ)), dim3(256), 0, stream>>>(q, Kh, Vh, o);
}